// Round 1
// baseline (130.272 us; speedup 1.0000x reference)
//
#include <hip/hip_runtime.h>
#include <hip/hip_bf16.h>
#include <stdint.h>

#define B_ 4
#define T_ 64
#define L_ 4096
#define D_ 4096

using bf8   = __attribute__((ext_vector_type(8))) short;   // 8 bf16 (4 VGPRs)
using f32x4 = __attribute__((ext_vector_type(4))) float;   // MFMA accumulator

// round-to-nearest-even fp32 -> bf16 (bit pattern in ushort)
__device__ __forceinline__ unsigned short f2bf(float f) {
    union { float f; unsigned int u; } v;
    v.f = f;
    unsigned int r = v.u + 0x7fffu + ((v.u >> 16) & 1u);
    return (unsigned short)(r >> 16);
}

// XOR swizzle on 16B chunks within a 128B LDS row; same fn on write & read.
__device__ __forceinline__ int swz16(int row, int byteoff) {
    return byteoff ^ (((row ^ (row >> 3)) & 7) << 4);
}

// MFMA fragment read: row = tile row (includes lane&15), kk = which 32-wide K half.
// Lane layout for mfma_f32_16x16x32_bf16: A row = lane&15, k = (lane>>4)*8 + j.
__device__ __forceinline__ bf8 read_frag(const unsigned short* lds, int row, int kk, int lane) {
    int byte = kk * 64 + ((lane >> 4) << 4);
    int off  = row * 128 + swz16(row, byte);
    return *reinterpret_cast<const bf8*>(reinterpret_cast<const char*>(lds) + off);
}

// ---------------- Kernel 1: scores[b,t,l] = (Q[t,:] . mask[b,l,:]) / 64 ----------------
// grid (L/64, B), 256 threads. Both operands K(=d)-contiguous ("B^T" GEMM).
__global__ __launch_bounds__(256, 1) void k_scores(
    const float* __restrict__ mask, const float* __restrict__ Q,
    float* __restrict__ scores) {
    __shared__ unsigned short lA[2][64 * 64];
    __shared__ unsigned short lB[2][64 * 64];
    const int tid  = threadIdx.x;
    const int lane = tid & 63;
    const int wave = tid >> 6;
    const int wm = wave >> 1, wn = wave & 1;     // 2x2 waves, 32x32 each
    const int b  = blockIdx.y;
    const int l0 = blockIdx.x * 64;
    const float* __restrict__ Mb = mask + (size_t)b * L_ * D_;

    f32x4 acc[2][2] = {};
    float4 ra[4], rb[4];

    auto loadTiles = [&](int k0) {
#pragma unroll
        for (int s = 0; s < 4; ++s) {
            int slot = tid + s * 256;
            int r = slot >> 4, c4 = slot & 15;
            ra[s] = *(reinterpret_cast<const float4*>(Q  + (size_t)r * D_ + k0) + c4);
            rb[s] = *(reinterpret_cast<const float4*>(Mb + (size_t)(l0 + r) * D_ + k0) + c4);
        }
    };
    auto writeTiles = [&](int buf) {
#pragma unroll
        for (int s = 0; s < 4; ++s) {
            int slot = tid + s * 256;
            int r = slot >> 4, c4 = slot & 15;
            int off = r * 128 + swz16(r, c4 * 8);
            ushort4 ua, ub;
            ua.x = f2bf(ra[s].x); ua.y = f2bf(ra[s].y); ua.z = f2bf(ra[s].z); ua.w = f2bf(ra[s].w);
            ub.x = f2bf(rb[s].x); ub.y = f2bf(rb[s].y); ub.z = f2bf(rb[s].z); ub.w = f2bf(rb[s].w);
            *reinterpret_cast<ushort4*>(reinterpret_cast<char*>(lA[buf]) + off) = ua;
            *reinterpret_cast<ushort4*>(reinterpret_cast<char*>(lB[buf]) + off) = ub;
        }
    };

    loadTiles(0);
    writeTiles(0);
    __syncthreads();
    const int NT = D_ / 64;
    for (int kt = 0; kt < NT; ++kt) {
        int cur = kt & 1;
        if (kt + 1 < NT) loadTiles((kt + 1) * 64);   // issue next-tile global loads early
#pragma unroll
        for (int kk = 0; kk < 2; ++kk) {
            bf8 a0 = read_frag(lA[cur], wm * 32 +      (lane & 15), kk, lane);
            bf8 a1 = read_frag(lA[cur], wm * 32 + 16 + (lane & 15), kk, lane);
            bf8 b0 = read_frag(lB[cur], wn * 32 +      (lane & 15), kk, lane);
            bf8 b1 = read_frag(lB[cur], wn * 32 + 16 + (lane & 15), kk, lane);
            acc[0][0] = __builtin_amdgcn_mfma_f32_16x16x32_bf16(a0, b0, acc[0][0], 0, 0, 0);
            acc[0][1] = __builtin_amdgcn_mfma_f32_16x16x32_bf16(a0, b1, acc[0][1], 0, 0, 0);
            acc[1][0] = __builtin_amdgcn_mfma_f32_16x16x32_bf16(a1, b0, acc[1][0], 0, 0, 0);
            acc[1][1] = __builtin_amdgcn_mfma_f32_16x16x32_bf16(a1, b1, acc[1][1], 0, 0, 0);
        }
        if (kt + 1 < NT) writeTiles(cur ^ 1);        // vmcnt waits here, overlapped with MFMA
        __syncthreads();
    }

    // C/D layout: col = lane&15, row = (lane>>4)*4 + reg  (m89-verified)
    const int rgrp = (lane >> 4) * 4;
    const int cidx = lane & 15;
#pragma unroll
    for (int mi = 0; mi < 2; ++mi)
#pragma unroll
        for (int nj = 0; nj < 2; ++nj)
#pragma unroll
            for (int r = 0; r < 4; ++r) {
                int t = wm * 32 + mi * 16 + rgrp + r;
                int l = l0 + wn * 32 + nj * 16 + cidx;
                scores[((size_t)b * T_ + t) * L_ + l] = acc[mi][nj][r] * 0.015625f; // 1/sqrt(4096)
            }
}

// ---------------- Kernel 2: masked softmax over L, fp32 scores -> bf16 attn ----------------
// grid B*T, 256 threads; each thread holds 16 elements in registers.
__global__ __launch_bounds__(256, 4) void k_softmax(
    const float* __restrict__ scores, const int* __restrict__ am,
    unsigned short* __restrict__ attn) {
    const int row  = blockIdx.x;                 // b*T + t
    const int tid  = threadIdx.x;
    const int lane = tid & 63;
    const int wave = tid >> 6;
    const float* __restrict__ s = scores + (size_t)row * L_;
    const int*   __restrict__ m = am     + (size_t)row * L_;
    __shared__ float redmax[4], redsum[4];

    float v[16];
#pragma unroll
    for (int j = 0; j < 4; ++j) {
        float4 f = *(reinterpret_cast<const float4*>(s) + tid + j * 256);
        int4   q = *(reinterpret_cast<const int4*>(m)   + tid + j * 256);
        v[j * 4 + 0] = q.x ? -1.0e9f : f.x;
        v[j * 4 + 1] = q.y ? -1.0e9f : f.y;
        v[j * 4 + 2] = q.z ? -1.0e9f : f.z;
        v[j * 4 + 3] = q.w ? -1.0e9f : f.w;
    }
    float mx = -3.0e38f;
#pragma unroll
    for (int i = 0; i < 16; ++i) mx = fmaxf(mx, v[i]);
#pragma unroll
    for (int off = 32; off; off >>= 1) mx = fmaxf(mx, __shfl_xor(mx, off, 64));
    if (lane == 0) redmax[wave] = mx;
    __syncthreads();
    mx = fmaxf(fmaxf(redmax[0], redmax[1]), fmaxf(redmax[2], redmax[3]));

    float z = 0.f;
#pragma unroll
    for (int i = 0; i < 16; ++i) {
        v[i] = exp2f((v[i] - mx) * 1.4426950408889634f);
        z += v[i];
    }
#pragma unroll
    for (int off = 32; off; off >>= 1) z += __shfl_xor(z, off, 64);
    if (lane == 0) redsum[wave] = z;
    __syncthreads();
    z = (redsum[0] + redsum[1]) + (redsum[2] + redsum[3]);
    float inv = 1.0f / z;

    unsigned short* __restrict__ arow = attn + (size_t)row * L_;
#pragma unroll
    for (int j = 0; j < 4; ++j) {
        ushort4 u;
        u.x = f2bf(v[j * 4 + 0] * inv);
        u.y = f2bf(v[j * 4 + 1] * inv);
        u.z = f2bf(v[j * 4 + 2] * inv);
        u.w = f2bf(v[j * 4 + 3] * inv);
        *(reinterpret_cast<ushort4*>(arow) + tid + j * 256) = u;
    }
}

// ---------------- Kernel 3: context[b,t,d] = sum_l attn[b,t,l] * mask[b,l,d] ----------------
// grid (D/64, B), 256 threads. B-tile (mask) staged TRANSPOSED into LDS as [d][l] bf16.
__global__ __launch_bounds__(256, 1) void k_context(
    const float* __restrict__ mask, const unsigned short* __restrict__ attn,
    float* __restrict__ out) {
    __shared__ unsigned short lA[2][64 * 64];   // [t][l]
    __shared__ unsigned short lB[2][64 * 64];   // [d][l] (transposed)
    const int tid  = threadIdx.x;
    const int lane = tid & 63;
    const int wave = tid >> 6;
    const int wm = wave >> 1, wn = wave & 1;
    const int b  = blockIdx.y;
    const int d0 = blockIdx.x * 64;
    const float*          __restrict__ Mb = mask + (size_t)b * L_ * D_;
    const unsigned short* __restrict__ Ab = attn + (size_t)b * T_ * L_;

    f32x4 acc[2][2] = {};
    uint4  raA[2];
    float4 rbB[4];

    auto loadTiles = [&](int k0) {
#pragma unroll
        for (int s = 0; s < 2; ++s) {
            int slot = tid + s * 256;
            int r = slot >> 3, c8 = slot & 7;
            raA[s] = *(reinterpret_cast<const uint4*>(Ab + (size_t)r * L_ + k0) + c8);
        }
#pragma unroll
        for (int s = 0; s < 4; ++s) {
            int slot = tid + s * 256;
            int kl = slot >> 4, d4 = slot & 15;
            rbB[s] = *(reinterpret_cast<const float4*>(Mb + (size_t)(k0 + kl) * D_ + d0) + d4);
        }
    };
    auto writeTiles = [&](int buf) {
#pragma unroll
        for (int s = 0; s < 2; ++s) {
            int slot = tid + s * 256;
            int r = slot >> 3, c8 = slot & 7;
            int off = r * 128 + swz16(r, c8 * 16);
            *reinterpret_cast<uint4*>(reinterpret_cast<char*>(lA[buf]) + off) = raA[s];
        }
#pragma unroll
        for (int s = 0; s < 4; ++s) {
            int slot = tid + s * 256;
            int kl = slot >> 4, d4 = slot & 15;
            float fv[4] = { rbB[s].x, rbB[s].y, rbB[s].z, rbB[s].w };
#pragma unroll
            for (int i = 0; i < 4; ++i) {
                int d = d4 * 4 + i;
                int off = d * 128 + swz16(d, kl * 2);
                *reinterpret_cast<unsigned short*>(reinterpret_cast<char*>(lB[buf]) + off) = f2bf(fv[i]);
            }
        }
    };

    loadTiles(0);
    writeTiles(0);
    __syncthreads();
    const int NT = L_ / 64;
    for (int kt = 0; kt < NT; ++kt) {
        int cur = kt & 1;
        if (kt + 1 < NT) loadTiles((kt + 1) * 64);
#pragma unroll
        for (int kk = 0; kk < 2; ++kk) {
            bf8 a0 = read_frag(lA[cur], wm * 32 +      (lane & 15), kk, lane);
            bf8 a1 = read_frag(lA[cur], wm * 32 + 16 + (lane & 15), kk, lane);
            bf8 b0 = read_frag(lB[cur], wn * 32 +      (lane & 15), kk, lane);
            bf8 b1 = read_frag(lB[cur], wn * 32 + 16 + (lane & 15), kk, lane);
            acc[0][0] = __builtin_amdgcn_mfma_f32_16x16x32_bf16(a0, b0, acc[0][0], 0, 0, 0);
            acc[0][1] = __builtin_amdgcn_mfma_f32_16x16x32_bf16(a0, b1, acc[0][1], 0, 0, 0);
            acc[1][0] = __builtin_amdgcn_mfma_f32_16x16x32_bf16(a1, b0, acc[1][0], 0, 0, 0);
            acc[1][1] = __builtin_amdgcn_mfma_f32_16x16x32_bf16(a1, b1, acc[1][1], 0, 0, 0);
        }
        if (kt + 1 < NT) writeTiles(cur ^ 1);
        __syncthreads();
    }

    const int rgrp = (lane >> 4) * 4;
    const int cidx = lane & 15;
#pragma unroll
    for (int mi = 0; mi < 2; ++mi)
#pragma unroll
        for (int nj = 0; nj < 2; ++nj)
#pragma unroll
            for (int r = 0; r < 4; ++r) {
                int t = wm * 32 + mi * 16 + rgrp + r;
                int d = d0 + wn * 32 + nj * 16 + cidx;
                out[((size_t)b * T_ + t) * D_ + d] = acc[mi][nj][r];
            }
}

extern "C" void kernel_launch(void* const* d_in, const int* in_sizes, int n_in,
                              void* d_out, int out_size, void* d_ws, size_t ws_size,
                              hipStream_t stream) {
    const float* mask = (const float*)d_in[0];        // [B, L, D] fp32
    const float* Q    = (const float*)d_in[1];        // [1, T, D] fp32
    const int*   am   = (const int*)d_in[2];          // [B, T, L] int (bool)
    float* out = (float*)d_out;                       // [B, T, D] fp32
    unsigned short* attn = (unsigned short*)d_ws;     // [B, T, L] bf16 (2 MB)

    // Pass 1: raw scaled scores into d_out (same element count as output: T*L == T*D)
    k_scores<<<dim3(L_ / 64, B_), 256, 0, stream>>>(mask, Q, out);
    // Pass 2: masked softmax, bf16 attn weights into workspace
    k_softmax<<<dim3(B_ * T_), 256, 0, stream>>>(out, am, attn);
    // Pass 3: context = attn @ mask, overwrite d_out
    k_context<<<dim3(D_ / 64, B_), 256, 0, stream>>>(mask, attn, out);
}